// Round 11
// baseline (191.855 us; speedup 1.0000x reference)
//
#include <hip/hip_runtime.h>
#include <math.h>

// DSHW — R11: zero-LDS scan. R10 killed the DVFS theory (8x load, VALUBusy
// 8x, time unchanged) -> genuine ~370 cyc/step stall. Unified explanation of
// the whole ladder: exposed LDS round-trip latency via in-order lgkm
// retirement + conservative waitcnt (4-bit lgkmcnt, ~14 outstanding ops ->
// near-lgkmcnt(0) waits each step draining the just-issued ds_read ~120cyc +
// write + vm drain ~200cyc = ~350). R11 removes ALL LDS: wc[168]+Ic[24] live
// in registers with compile-time indices (peel 2 steps; 3 super-groups of 168
// fully-unrolled steps, s0=2,170,338 — 168 = 0 mod 24 and 12 so every phase
// index is static in j; 6-step tail + 2-step drain). Dataflow and all f64
// expressions identical to R8 -> bit-identical outputs (absmax 1.6106e9).

#define P1c   24
#define P2c   168
#define NSTEP 512
#define BSc   64
#define NFc   16
#define MAXH  336
#define NT    32
#define NSERIES 1024

#define OFF_FC   0
#define OFF_YH   (BSc * MAXH * NFc)
#define OFF_E    (OFF_YH + BSc * NSTEP * NFc)
#define OFF_IC   (OFF_E  + BSc * NSTEP * NFc)
#define OFF_WC   (OFF_IC + BSc * P1c * NFc)
#define OFF_T    (OFF_WC + BSc * P2c * NFc)
#define OFF_S    (OFF_T  + BSc * NFc)

#define WS_NEED ((size_t)194 * NSERIES * sizeof(double))

__device__ __forceinline__ double nrcp(double a) {
    double x = __builtin_amdgcn_rcp(a);          // v_rcp_f64, no VCC
    x = fma(fma(-a, x, 1.0), x, x);
    x = fma(fma(-a, x, 1.0), x, x);              // ~1 ulp
    return x;
}

// ---------------------------------------------------------------------------
// Kernel 1: init + scan, all state in registers (no LDS anywhere).
// ---------------------------------------------------------------------------
__global__ __launch_bounds__(NT, 1)
void dshw_scan9(const float* __restrict__ y,
                const float* __restrict__ alphas,
                const float* __restrict__ betas,
                const float* __restrict__ gammas,
                const float* __restrict__ omegas,
                double* __restrict__ wsst,
                float* __restrict__ out)
{
    const int tid = threadIdx.x;
    const int g   = blockIdx.x * NT + tid;
    const int bb  = g >> 4;
    const int f   = g & 15;

    const float* __restrict__ yb = y + (size_t)bb * NSTEP * NFc + f;

    const double al = 1.0 / (1.0 + exp(-(double)alphas[f]));
    const double be = 1.0 / (1.0 + exp(-(double)betas[f]));
    const double ga = 1.0 / (1.0 + exp(-(double)gammas[f]));
    const double om = 1.0 / (1.0 + exp(-(double)omegas[f]));
    const double one_m_al = 1.0 - al, one_m_be = 1.0 - be;
    const double one_m_ga = 1.0 - ga, one_m_om = 1.0 - om;

    // ---------------- init (expressions identical to R8; wc/Ic in regs) ----
    double Ic[P1c];           // all indices compile-time
    double wc[P2c];           // all indices compile-time

    double sum48 = 0.0;
    #pragma unroll
    for (int ph = 0; ph < P1c; ++ph) {
        double v0 = (double)yb[ph * NFc];
        double v1 = (double)yb[(ph + P1c) * NFc];
        Ic[ph] = 0.5 * (v0 + v1);
        sum48 += v0 + v1;
    }
    const double inv_mean48 = 48.0 * nrcp(sum48);
    #pragma unroll
    for (int ph = 0; ph < P1c; ++ph) Ic[ph] *= inv_mean48;

    double sa = 0.0, sb = 0.0;
    #pragma unroll
    for (int i = 0; i < P2c; ++i) {
        double v0 = (double)yb[i * NFc];
        double v1 = (double)yb[(i + P2c) * NFc];
        wc[i] = 0.5 * (v0 + v1);
        sa += v0; sb += v1;
    }
    const double mean336     = (sa + sb) * (1.0 / 336.0);
    const double inv_mean336 = nrcp(mean336);
    #pragma unroll
    for (int ph = 0; ph < P1c; ++ph) {
        double rI = inv_mean336 * nrcp(Ic[ph]);
        #pragma unroll
        for (int r = 0; r < 7; ++r) wc[ph + 24 * r] *= rI;
    }

    double tt = 0.5 * ((sa - sb) * (1.0 / (168.0 * 168.0)) +
                       ((double)yb[(P2c - 1) * NFc] - (double)yb[0]) * (1.0 / 168.0));
    double ss = mean336 - 168.5 * tt;

    // ---------------- scan ----------------
    float* __restrict__ yh_o = out + OFF_YH + (size_t)bb * NSTEP * NFc + f;
    float* __restrict__ e_o  = out + OFF_E  + (size_t)bb * NSTEP * NFc + f;

    float  yring[12];         // slot s%12 holds y_s when step s executes
    double ur[2], snr[2];     // u_{s-2}, snew_{s-2} (slot s%2, read-then-write)

    #pragma unroll
    for (int k = 0; k < 12; ++k) yring[k] = yb[k * NFc];

    // ---- peel steps 0, 1 (no D) ----
    #pragma unroll
    for (int s = 0; s < 2; ++s) {
        double yv  = (double)yring[s];
        double iw  = Ic[s] * wc[s];
        double u   = yv * nrcp(iw);
        double spt = ss + tt;
        double yhat = spt * iw;
        double snew = al * u + one_m_al * spt;
        double tnew = be * (snew - ss) + one_m_be * tt;
        yh_o[s * NFc] = (float)yhat;
        e_o[s * NFc]  = (float)(yv - yhat);
        ss = snew; tt = tnew;
        ur[s]  = u;
        snr[s] = snew;
        yring[s] = yb[(s + 12) * NFc];
    }

    // ---- 3 super-groups of 168 steps: s = s0 + j, s0 in {2,170,338} ----
    // 168 = 0 mod 24 and mod 12, s0 = 2 mod everything -> static indices in j.
    for (int s0 = 2; s0 <= 338; s0 += 168) {
        #pragma unroll
        for (int j = 0; j < 168; ++j) {
            const int p168 = (2 + j) % 168;   // read phase (s%168)
            const int p24  = (2 + j) % 24;    // read phase (s%24)
            const int py   = (2 + j) % 12;    // y slot (s%12)
            const int d168 = j % 168;         // D phase ((s-2)%168)
            const int d24  = j % 24;          // D phase ((s-2)%24)

            double yv = (double)yring[py];
            int pidx = s0 + j + 12; pidx = (pidx < NSTEP) ? pidx : (NSTEP - 1);
            yring[py] = yb[pidx * NFc];       // reload after use

            double iw  = Ic[p24] * wc[p168];  // off-chain (regs, scheduler-free)
            double u   = yv * nrcp(iw);
            double spt = ss + tt;             // the serial chain
            double yhat = spt * iw;
            double snew = al * u + one_m_al * spt;
            double tnew = be * (snew - ss) + one_m_be * tt;
            yh_o[(s0 + j) * NFc] = (float)yhat;
            e_o[(s0 + j) * NFc]  = (float)(yv - yhat);
            ss = snew; tt = tnew;

            // D for step s-2 (register RMW, static indices)
            double uD  = ur[j % 2];  ur[j % 2]  = u;
            double snD = snr[j % 2]; snr[j % 2] = snew;
            double r   = nrcp(snD);
            double uDr = uD * r;
            Ic[d24]   *= fma(ga, uDr, one_m_ga);
            wc[d168]  *= fma(om, uDr, one_m_om);
        }
    }

    // ---- tail: steps 506..511 (506 = 2 mod 168/24/12) ----
    #pragma unroll
    for (int k = 0; k < 6; ++k) {
        const int s    = 506 + k;
        const int p168 = (2 + k) % 168;
        const int p24  = (2 + k) % 24;
        const int py   = (2 + k) % 12;

        double yv = (double)yring[py];
        double iw  = Ic[p24] * wc[p168];
        double u   = yv * nrcp(iw);
        double spt = ss + tt;
        double yhat = spt * iw;
        double snew = al * u + one_m_al * spt;
        double tnew = be * (snew - ss) + one_m_be * tt;
        yh_o[s * NFc] = (float)yhat;
        e_o[s * NFc]  = (float)(yv - yhat);
        ss = snew; tt = tnew;

        double uD  = ur[k % 2];  ur[k % 2]  = u;
        double snD = snr[k % 2]; snr[k % 2] = snew;
        double r   = nrcp(snD);
        double uDr = uD * r;
        Ic[k]  *= fma(ga, uDr, one_m_ga);     // (s-2)%24 = k
        wc[k]  *= fma(om, uDr, one_m_om);     // (s-2)%168 = k
    }
    // ---- drain D: steps 510 (phase 6), 511 (phase 7) ----
    {
        double r   = nrcp(snr[0]);            // snew_510
        double uDr = ur[0] * r;               // u_510
        Ic[6] *= fma(ga, uDr, one_m_ga);
        wc[6] *= fma(om, uDr, one_m_om);
    }
    {
        double r   = nrcp(snr[1]);            // snew_511
        double uDr = ur[1] * r;               // u_511
        Ic[7] *= fma(ga, uDr, one_m_ga);
        wc[7] *= fma(om, uDr, one_m_om);
    }

    // ---- dump raw f64 state, item-major (coalesced) ----
    #pragma unroll
    for (int p = 0; p < P1c; ++p)  wsst[(size_t)p * NSERIES + g] = Ic[p];
    #pragma unroll
    for (int p = 0; p < P2c; ++p)  wsst[(size_t)(P1c + p) * NSERIES + g] = wc[p];
    wsst[(size_t)192 * NSERIES + g] = ss;
    wsst[(size_t)193 * NSERIES + g] = tt;

    out[OFF_T + bb * NFc + f] = (float)tt;
    out[OFF_S + bb * NFc + f] = (float)ss;
}

// ---------------------------------------------------------------------------
// Kernel 2: parallel epilogue — fcast + rolled Ic/wc from f64 ws state.
// ---------------------------------------------------------------------------
__global__ __launch_bounds__(256)
void dshw_epilogue(const double* __restrict__ ws, float* __restrict__ out)
{
    const int f      = threadIdx.x & 15;
    const int isub   = threadIdx.x >> 4;
    const int bb     = blockIdx.x & 63;
    const int chunk  = blockIdx.x >> 6;
    const int item   = chunk * 16 + isub;
    const int series = bb * NFc + f;

    if (item < MAXH) {
        const int k = item;
        double cb = ws[(size_t)((k + 8) % P1c) * NSERIES + series];
        double cc = ws[(size_t)(P1c + (k + 8) % P2c) * NSERIES + series];
        double ssv = ws[(size_t)192 * NSERIES + series];
        double ttv = ws[(size_t)193 * NSERIES + series];
        double ca = ssv + (double)(k + 1) * ttv;
        out[OFF_FC + (bb * MAXH + k) * NFc + f] = (float)(ca * cb * cc);
    } else if (item < MAXH + P1c) {
        const int j = item - MAXH;
        out[OFF_IC + (bb * P1c + j) * NFc + f] =
            (float)ws[(size_t)((j + 8) % P1c) * NSERIES + series];
    } else if (item < MAXH + P1c + P2c) {
        const int j = item - (MAXH + P1c);
        out[OFF_WC + (bb * P2c + j) * NFc + f] =
            (float)ws[(size_t)(P1c + (j + 8) % P2c) * NSERIES + series];
    }
}

// ---------------------------------------------------------------------------
// Fallback (R2 fused kernel, verbatim) — used only if ws is too small.
// ---------------------------------------------------------------------------
__global__ __launch_bounds__(32, 1)
void dshw_fused(const float* __restrict__ y,
                const float* __restrict__ alphas,
                const float* __restrict__ betas,
                const float* __restrict__ gammas,
                const float* __restrict__ omegas,
                float* __restrict__ out)
{
    __shared__ double sIc[P1c][32];
    __shared__ double sWc[P2c][32];

    const int tid = threadIdx.x;
    const int g   = blockIdx.x * 32 + tid;
    const int bb  = g >> 4;
    const int f   = g & 15;

    const float* __restrict__ yb = y + (size_t)bb * NSTEP * NFc + f;

    const double al = 1.0 / (1.0 + exp(-(double)alphas[f]));
    const double be = 1.0 / (1.0 + exp(-(double)betas[f]));
    const double ga = 1.0 / (1.0 + exp(-(double)gammas[f]));
    const double om = 1.0 / (1.0 + exp(-(double)omegas[f]));

    double sum48 = 0.0;
    #pragma unroll
    for (int ph = 0; ph < P1c; ++ph) {
        double v0 = (double)yb[ph * NFc];
        double v1 = (double)yb[(ph + P1c) * NFc];
        sIc[ph][tid] = 0.5 * (v0 + v1);
        sum48 += v0 + v1;
    }
    const double inv_mean48 = 48.0 / sum48;
    #pragma unroll
    for (int ph = 0; ph < P1c; ++ph) sIc[ph][tid] *= inv_mean48;

    double sum168a = 0.0, sum168b = 0.0;
    for (int i = 0; i < P2c; ++i) {
        double v0 = (double)yb[i * NFc];
        double v1 = (double)yb[(i + P2c) * NFc];
        sWc[i][tid] = 0.5 * (v0 + v1);
        sum168a += v0;
        sum168b += v1;
    }
    const double mean336 = (sum168a + sum168b) * (1.0 / 336.0);
    for (int i = 0; i < P2c; ++i) {
        sWc[i][tid] = (sWc[i][tid] / mean336) / sIc[i % P1c][tid];
    }

    double tt = 0.5 * ((sum168a - sum168b) * (1.0 / (168.0 * 168.0)) +
                       ((double)yb[(P2c - 1) * NFc] - (double)yb[0]) * (1.0 / 168.0));
    double ss = mean336 - 168.5 * tt;

    float* __restrict__ yh_o = out + OFF_YH + (size_t)bb * NSTEP * NFc + f;
    float* __restrict__ e_o  = out + OFF_E  + (size_t)bb * NSTEP * NFc + f;

    int i1 = 0, i2 = 0;
    int i1p = 2, i2p = 2;

    double Icv0 = sIc[0][tid], Icv1 = sIc[1][tid];
    double wcv0 = sWc[0][tid], wcv1 = sWc[1][tid];
    double yt0 = (double)yb[0 * NFc], yt1 = (double)yb[1 * NFc];
    double yt2 = (double)yb[2 * NFc], yt3 = (double)yb[3 * NFc];

    #pragma unroll 4
    for (int step = 0; step < NSTEP; ++step) {
        double Icv2 = sIc[i1p][tid];
        double wcv2 = sWc[i2p][tid];
        int    pidx = step + 4; pidx = (pidx < NSTEP) ? pidx : (NSTEP - 1);
        double yt4  = (double)yb[pidx * NFc];

        double iw     = Icv0 * wcv0;
        double spt    = ss + tt;
        double yhat   = spt * iw;
        double inv_iw = 1.0 / iw;
        double u      = yt0 * inv_iw;
        double snew   = al * u + (1.0 - al) * spt;
        double tnew   = be * (snew - ss) + (1.0 - be) * tt;
        double q      = yt0 / snew;
        double icn    = ga * (q * (inv_iw * Icv0)) + (1.0 - ga) * Icv0;
        double wcn    = om * (q * (inv_iw * wcv0)) + (1.0 - om) * wcv0;

        sIc[i1][tid] = icn;
        sWc[i2][tid] = wcn;
        yh_o[step * NFc] = (float)yhat;
        e_o[step * NFc]  = (float)(yt0 - yhat);

        ss = snew; tt = tnew;
        Icv0 = Icv1; Icv1 = Icv2;
        wcv0 = wcv1; wcv1 = wcv2;
        yt0 = yt1; yt1 = yt2; yt2 = yt3; yt3 = yt4;
        i1  = (i1  + 1 == P1c) ? 0 : i1  + 1;
        i2  = (i2  + 1 == P2c) ? 0 : i2  + 1;
        i1p = (i1p + 1 == P1c) ? 0 : i1p + 1;
        i2p = (i2p + 1 == P2c) ? 0 : i2p + 1;
    }

    float* __restrict__ fc_o = out + OFF_FC + (size_t)bb * MAXH * NFc + f;
    {
        int k1 = 8, k2 = 8;
        for (int k = 0; k < MAXH; ++k) {
            double cb = sIc[k1][tid];
            double cc = sWc[k2][tid];
            double ca = ss + (double)(k + 1) * tt;
            fc_o[k * NFc] = (float)(ca * cb * cc);
            k1 = (k1 + 1 == P1c) ? 0 : k1 + 1;
            k2 = (k2 + 1 == P2c) ? 0 : k2 + 1;
        }
    }
    {
        float* __restrict__ ic_o = out + OFF_IC + (size_t)bb * P1c * NFc + f;
        int k1 = 8;
        #pragma unroll
        for (int j = 0; j < P1c; ++j) {
            ic_o[j * NFc] = (float)sIc[k1][tid];
            k1 = (k1 + 1 == P1c) ? 0 : k1 + 1;
        }
    }
    {
        float* __restrict__ wc_o = out + OFF_WC + (size_t)bb * P2c * NFc + f;
        int k2 = 8;
        for (int j = 0; j < P2c; ++j) {
            wc_o[j * NFc] = (float)sWc[k2][tid];
            k2 = (k2 + 1 == P2c) ? 0 : k2 + 1;
        }
    }

    out[OFF_T + bb * NFc + f] = (float)tt;
    out[OFF_S + bb * NFc + f] = (float)ss;
}

extern "C" void kernel_launch(void* const* d_in, const int* in_sizes, int n_in,
                              void* d_out, int out_size, void* d_ws, size_t ws_size,
                              hipStream_t stream)
{
    const float* y      = (const float*)d_in[0];
    const float* alphas = (const float*)d_in[1];
    const float* betas  = (const float*)d_in[2];
    const float* gammas = (const float*)d_in[3];
    const float* omegas = (const float*)d_in[4];
    float* out = (float*)d_out;

    if (ws_size >= WS_NEED) {
        double* wsst = (double*)d_ws;
        hipLaunchKernelGGL(dshw_scan9, dim3(NSERIES / NT), dim3(NT), 0, stream,
                           y, alphas, betas, gammas, omegas, wsst, out);
        hipLaunchKernelGGL(dshw_epilogue, dim3(33 * BSc), dim3(256), 0, stream,
                           wsst, out);
    } else {
        hipLaunchKernelGGL(dshw_fused, dim3(NSERIES / 32), dim3(32), 0, stream,
                           y, alphas, betas, gammas, omegas, out);
    }
}